// Round 11
// baseline (201.912 us; speedup 1.0000x reference)
//
#include <hip/hip_runtime.h>

// WeightedTensorProduct: N=16384 nodes, F=128, ranks 0..3 (sizes 1,3,9,27).
// x,y: [N, 5120] f32 (row: [128] | [128][3] | [128][9] | [128][27]).
// weights: [23][128] f32. out: [N, 5120] f32.
//
// Wave-autonomous + double-buffered prefetch: one 64-lane wave per block,
// quarter-node (32 features), 2 x 10 KB LDS buffers, 32 nodes per block
// (grid = 2048 = 8 resident blocks/CU). NO barriers (single wave: counted
// vmcnt + lgkmcnt only). Per iteration the next node's global->LDS DMA is
// issued before computing the current node; s_waitcnt vmcnt(15) retires
// exactly the current node's loads and leaves prefetch + NT stores in
// flight. Fixes round 10's workgroup-launch-rate ceiling (one-shot blocks
// lived ~5us each; CP tops out ~350 waves/us -> only ~7 waves/CU resident).
// No waves/EU hint in __launch_bounds__ (caps VGPR -> spills, rounds 3-5/8/9).

#define FF 128
#define ROW 5120
#define QROW 1280    // packed quarter-row floats (32 features x 40)
#define CHUNK 32     // nodes per block

typedef float floatx4 __attribute__((ext_vector_type(4)));

__device__ __constant__ float NORMS[23] = {
    1.0f, 1.0f, 2.0f/3.0f, 0.4f,                          // (0,0,0)(1,1,0)(2,2,0)(3,3,0)
    1.0f, 1.0f, 1.0f, 1.0f, 2.0f/3.0f, 2.0f/3.0f,         // l3=1 paths
    1.0f, 0.75f, 1.0f, 1.0f, 1.0f, 1.0f, 0.75f,           // l3=2 paths
    1.0f, 5.0f/9.0f, 5.0f/9.0f, 5.0f/6.0f, 1.0f, 5.0f/6.0f // l3=3 paths
};

#define GL2LDS(g, l)  __builtin_amdgcn_global_load_lds(                      \
        (const __attribute__((address_space(1))) void*)(g),                  \
        (__attribute__((address_space(3))) void*)(l), 16, 0, 0)

__global__ __launch_bounds__(64) void wtp_kernel(
    const float* __restrict__ x, const float* __restrict__ y,
    const float* __restrict__ w, float* __restrict__ out)
{
    __shared__ float buf[2][2 * QROW];   // 2 x 10 KB: packed x-quarter | y-quarter

    const int lane  = threadIdx.x;
    const int f     = lane & 31;              // local feature
    const int h     = lane >> 5;              // 0 -> l3=0,1,2 ; 1 -> l3=3
    const int fbase = (blockIdx.x & 3) << 5;  // 0,32,64,96
    const int first = (blockIdx.x >> 2) * CHUNK;

    // per-lane global offsets for the 5 DMA/store issues (packed layout:
    // r0 [0,32) r1 [32,128) r2 [128,416) r3 [416,1280); all boundaries %4==0)
    int goff[5];
    #pragma unroll
    for (int i = 0; i < 5; ++i) {
        const int o = i * 256 + lane * 4;
        int r;
        if      (o < 32)  r = fbase         + o;
        else if (o < 128) r = 128  + fbase*3  + (o - 32);
        else if (o < 416) r = 512  + fbase*9  + (o - 128);
        else              r = 1664 + fbase*27 + (o - 416);
        goff[i] = r;
    }

    // weights first; vmcnt(0) retires them so loop vmcnt counts stay exact
    float c[23];
    #pragma unroll
    for (int p = 0; p < 23; ++p) c[p] = NORMS[p] * w[p * FF + fbase + f];
    asm volatile("s_waitcnt vmcnt(0)" ::: "memory");

    // ---- prologue: DMA node `first` into buf[0] (10 loads) ----
    {
        const float* xr = x + (size_t)first * ROW;
        const float* yr = y + (size_t)first * ROW;
        #pragma unroll
        for (int i = 0; i < 5; ++i) {
            GL2LDS(xr + goff[i], &buf[0][i * 256]);
            GL2LDS(yr + goff[i], &buf[0][QROW + i * 256]);
        }
    }

    int cur = 0;
    for (int k = 0; k < CHUNK; ++k) {
        const int node = first + k;

        // ---- prefetch next node into the other buffer, counted wait ----
        if (k + 1 < CHUNK) {
            const float* xr = x + (size_t)(node + 1) * ROW;
            const float* yr = y + (size_t)(node + 1) * ROW;
            #pragma unroll
            for (int i = 0; i < 5; ++i) {
                GL2LDS(xr + goff[i], &buf[cur ^ 1][i * 256]);
                GL2LDS(yr + goff[i], &buf[cur ^ 1][QROW + i * 256]);
            }
            if (k == 0) {
                // queue: [node0 loads(10), node1 loads(10)] -> retire node0's
                asm volatile("s_waitcnt vmcnt(10)" ::: "memory");
            } else {
                // queue: [stores k-2(5), loads k(10), stores k-1(5), loads k+1(10)]
                // vmcnt(15) retires stores k-2 + loads k, leaves 15 in flight
                asm volatile("s_waitcnt vmcnt(15)" ::: "memory");
            }
        } else {
            // queue: [stores k-2(5), loads k(10), stores k-1(5)] -> retire loads k
            asm volatile("s_waitcnt vmcnt(5)" ::: "memory");
        }

        // ---- compute from buf[cur]: rank 0..2 -> regs, rank-3 from LDS ----
        const float* bx = &buf[cur][0];
        const float* by = &buf[cur][QROW];
        const float x0 = bx[f], y0 = by[f];
        float x1[3], y1[3], x2[9], y2[9];
        #pragma unroll
        for (int j = 0; j < 3; ++j)  x1[j] = bx[32  + f*3 + j];
        #pragma unroll
        for (int j = 0; j < 3; ++j)  y1[j] = by[32  + f*3 + j];
        #pragma unroll
        for (int j = 0; j < 9; ++j)  x2[j] = bx[128 + f*9 + j];
        #pragma unroll
        for (int j = 0; j < 9; ++j)  y2[j] = by[128 + f*9 + j];

        const float* bx3 = bx + 416 + f*27;   // stride 27 (odd) -> conflict-free
        const float* by3 = by + 416 + f*27;

        float o0, o1[3], o2[9], o3[27];

        if (h == 0) {
            // ---- l3 = 0 ----
            {
                float acc = c[0] * (x0 * y0);
                float d3 = 0.f;
                #pragma unroll
                for (int u = 0; u < 3; ++u) d3 += x1[u] * y1[u];
                acc += c[1] * d3;
                float d9 = 0.f;
                #pragma unroll
                for (int t = 0; t < 9; ++t) d9 += x2[t] * y2[t];
                acc += c[2] * d9;
                float d27 = 0.f;
                #pragma unroll
                for (int t = 0; t < 27; ++t) d27 += bx3[t] * by3[t];
                acc += c[3] * d27;
                o0 = acc;
            }
            // ---- l3 = 1 ----
            #pragma unroll
            for (int d = 0; d < 3; ++d) {
                float acc = c[4] * (x0 * y1[d]) + c[5] * (x1[d] * y0);
                float s6 = 0.f, s7 = 0.f, s8 = 0.f, s9 = 0.f;
                #pragma unroll
                for (int u = 0; u < 3; ++u) s6 += x1[u] * y2[u*3 + d];     // (1,2,1)
                #pragma unroll
                for (int u = 0; u < 3; ++u) s7 += x2[d*3 + u] * y1[u];     // (2,1,1)
                #pragma unroll
                for (int t = 0; t < 9; ++t) s8 += x2[t] * by3[t*3 + d];    // (2,3,1)
                #pragma unroll
                for (int t = 0; t < 9; ++t) s9 += bx3[d*9 + t] * y2[t];    // (3,2,1)
                o1[d] = acc + c[6]*s6 + c[7]*s7 + c[8]*s8 + c[9]*s9;
            }
            // ---- l3 = 2 ----  (t = a*3 + d)
            #pragma unroll
            for (int t = 0; t < 9; ++t) {
                const int a = t / 3, d = t % 3;
                float acc = c[10] * (x0 * y2[t]) + c[11] * (x1[a] * y1[d])
                          + c[13] * (x2[t] * y0);
                float s12 = 0.f, s14 = 0.f, s15 = 0.f, s16 = 0.f;
                #pragma unroll
                for (int u = 0; u < 3; ++u) s12 += x1[u] * by3[u*9 + t];       // (1,3,2)
                #pragma unroll
                for (int u = 0; u < 3; ++u) s14 += x2[a*3 + u] * y2[u*3 + d];  // (2,2,2)
                #pragma unroll
                for (int u = 0; u < 3; ++u) s15 += bx3[t*3 + u] * y1[u];       // (3,1,2)
                #pragma unroll
                for (int s = 0; s < 9; ++s) s16 += bx3[a*9 + s] * by3[s*3 + d];// (3,3,2)
                o2[t] = acc + c[12]*s12 + c[14]*s14 + c[15]*s15 + c[16]*s16;
            }
        } else {
            // ---- l3 = 3 ----  (q = a*9 + t9, also q = r*3 + e)
            #pragma unroll
            for (int q = 0; q < 27; ++q) {
                const int a = q / 9, t9 = q % 9, r = q / 3, e = q % 3;
                float acc = c[17] * (x0 * by3[q]) + c[18] * (x1[a] * y2[t9])
                          + c[19] * (x2[r] * y1[e]) + c[21] * (bx3[q] * y0);
                float s20 = 0.f, s22 = 0.f;
                #pragma unroll
                for (int u = 0; u < 3; ++u) s20 += x2[a*3 + u] * by3[u*9 + t9]; // (2,3,3)
                #pragma unroll
                for (int u = 0; u < 3; ++u) s22 += bx3[r*3 + u] * y2[u*3 + e];  // (3,2,3)
                o3[q] = acc + c[20]*s20 + c[22]*s22;
            }
        }

        // ---- stage outputs into the (now dead) x-region of buf[cur] ----
        // h=0 writes [0,416); h=1 writes [416,1280); all compute LDS reads
        // precede these in program order (lockstep exec-masked halves).
        float* B = &buf[cur][0];
        if (h == 0) {
            B[f] = o0;
            #pragma unroll
            for (int d = 0; d < 3; ++d) B[32  + f*3 + d] = o1[d];
            #pragma unroll
            for (int t = 0; t < 9; ++t) B[128 + f*9 + t] = o2[t];
        } else {
            #pragma unroll
            for (int q = 0; q < 27; ++q) B[416 + f*27 + q] = o3[q];
        }
        asm volatile("s_waitcnt lgkmcnt(0)" ::: "memory");  // stage-writes retired
        __builtin_amdgcn_sched_barrier(0);                  // keep readback below

        // ---- coalesced NT float4 store (same offsets as the DMA) ----
        float* orow = out + (size_t)node * ROW;
        #pragma unroll
        for (int i = 0; i < 5; ++i) {
            floatx4 v = *(const floatx4*)(B + i * 256 + lane * 4);
            __builtin_nontemporal_store(v, (floatx4*)(orow + goff[i]));
        }
        cur ^= 1;
    }
}

extern "C" void kernel_launch(void* const* d_in, const int* in_sizes, int n_in,
                              void* d_out, int out_size, void* d_ws, size_t ws_size,
                              hipStream_t stream) {
    const float* x = (const float*)d_in[0];
    const float* y = (const float*)d_in[1];
    const float* w = (const float*)d_in[2];
    float* out = (float*)d_out;

    const int n_nodes = in_sizes[0] / ROW;             // 16384
    dim3 grid((n_nodes / CHUNK) * 4), block(64);       // 2048 blocks = 8/CU
    hipLaunchKernelGGL(wtp_kernel, grid, block, 0, stream, x, y, w, out);
}

// Round 12
// 181.735 us; speedup vs baseline: 1.1110x; 1.1110x over previous
//
#include <hip/hip_runtime.h>

// WeightedTensorProduct: N=16384 nodes, F=128, ranks 0..3 (sizes 1,3,9,27).
// x,y: [N, 5120] f32 (row: [128] | [128][3] | [128][9] | [128][27]).
// weights: [23][128] f32. out: [N, 5120] f32.
//
// Round-7 champion structure (one-shot 128-thread blocks, half-node = 64
// features, wave-uniform l3-split, coalesced global->LDS DMA, LDS-staged NT
// stores) extended to TWO nodes per block with both nodes' DMA issued up
// front: 20 outstanding loads/wave during the first latency window (vs 10),
// counted vmcnt so node B's loads stay in flight through node A's
// compute+store. Tests the "sustained BW ~ in-flight VMEM streams" theory
// derived from rounds 3/9 (spill traffic accidentally sustained 4.6 TB/s).

#define FF 128
#define ROW 5120
#define HALFROW 2560   // packed half-row floats (64 features x 40)

typedef float floatx4 __attribute__((ext_vector_type(4)));

__device__ __constant__ float NORMS[23] = {
    1.0f, 1.0f, 2.0f/3.0f, 0.4f,                          // (0,0,0)(1,1,0)(2,2,0)(3,3,0)
    1.0f, 1.0f, 1.0f, 1.0f, 2.0f/3.0f, 2.0f/3.0f,         // l3=1 paths
    1.0f, 0.75f, 1.0f, 1.0f, 1.0f, 1.0f, 0.75f,           // l3=2 paths
    1.0f, 5.0f/9.0f, 5.0f/9.0f, 5.0f/6.0f, 1.0f, 5.0f/6.0f // l3=3 paths
};

#define GL2LDS(g, l)  __builtin_amdgcn_global_load_lds(                      \
        (const __attribute__((address_space(1))) void*)(g),                  \
        (__attribute__((address_space(3))) void*)(l), 16, 0, 0)

// compute one half-node from a packed LDS buffer (r0 [0,64) r1 [64,256)
// r2 [256,832) r3 [832,2560)); h is wave-uniform (0 -> l3=0,1,2 ; 1 -> l3=3)
__device__ __forceinline__ void compute_node(
    const float* __restrict__ bx, const float* __restrict__ by,
    const float* __restrict__ c, int f, int h,
    float& o0, float* o1, float* o2, float* o3)
{
    const float x0 = bx[f], y0 = by[f];
    float x1[3], y1[3], x2[9], y2[9];
    #pragma unroll
    for (int j = 0; j < 3; ++j)  x1[j] = bx[64  + f*3 + j];
    #pragma unroll
    for (int j = 0; j < 3; ++j)  y1[j] = by[64  + f*3 + j];
    #pragma unroll
    for (int j = 0; j < 9; ++j)  x2[j] = bx[256 + f*9 + j];
    #pragma unroll
    for (int j = 0; j < 9; ++j)  y2[j] = by[256 + f*9 + j];

    const float* bx3 = bx + 832 + f*27;   // stride 27 (odd) -> conflict-free
    const float* by3 = by + 832 + f*27;

    if (h == 0) {
        // ---- l3 = 0 ----
        {
            float acc = c[0] * (x0 * y0);
            float d3 = 0.f;
            #pragma unroll
            for (int u = 0; u < 3; ++u) d3 += x1[u] * y1[u];
            acc += c[1] * d3;
            float d9 = 0.f;
            #pragma unroll
            for (int t = 0; t < 9; ++t) d9 += x2[t] * y2[t];
            acc += c[2] * d9;
            float d27 = 0.f;
            #pragma unroll
            for (int t = 0; t < 27; ++t) d27 += bx3[t] * by3[t];
            acc += c[3] * d27;
            o0 = acc;
        }
        // ---- l3 = 1 ----
        #pragma unroll
        for (int d = 0; d < 3; ++d) {
            float acc = c[4] * (x0 * y1[d]) + c[5] * (x1[d] * y0);
            float s6 = 0.f, s7 = 0.f, s8 = 0.f, s9 = 0.f;
            #pragma unroll
            for (int u = 0; u < 3; ++u) s6 += x1[u] * y2[u*3 + d];     // (1,2,1)
            #pragma unroll
            for (int u = 0; u < 3; ++u) s7 += x2[d*3 + u] * y1[u];     // (2,1,1)
            #pragma unroll
            for (int t = 0; t < 9; ++t) s8 += x2[t] * by3[t*3 + d];    // (2,3,1)
            #pragma unroll
            for (int t = 0; t < 9; ++t) s9 += bx3[d*9 + t] * y2[t];    // (3,2,1)
            o1[d] = acc + c[6]*s6 + c[7]*s7 + c[8]*s8 + c[9]*s9;
        }
        // ---- l3 = 2 ----  (t = a*3 + d)
        #pragma unroll
        for (int t = 0; t < 9; ++t) {
            const int a = t / 3, d = t % 3;
            float acc = c[10] * (x0 * y2[t]) + c[11] * (x1[a] * y1[d])
                      + c[13] * (x2[t] * y0);
            float s12 = 0.f, s14 = 0.f, s15 = 0.f, s16 = 0.f;
            #pragma unroll
            for (int u = 0; u < 3; ++u) s12 += x1[u] * by3[u*9 + t];       // (1,3,2)
            #pragma unroll
            for (int u = 0; u < 3; ++u) s14 += x2[a*3 + u] * y2[u*3 + d];  // (2,2,2)
            #pragma unroll
            for (int u = 0; u < 3; ++u) s15 += bx3[t*3 + u] * y1[u];       // (3,1,2)
            #pragma unroll
            for (int s = 0; s < 9; ++s) s16 += bx3[a*9 + s] * by3[s*3 + d];// (3,3,2)
            o2[t] = acc + c[12]*s12 + c[14]*s14 + c[15]*s15 + c[16]*s16;
        }
    } else {
        // ---- l3 = 3 ----  (q = a*9 + t9, also q = r*3 + e)
        #pragma unroll
        for (int q = 0; q < 27; ++q) {
            const int a = q / 9, t9 = q % 9, r = q / 3, e = q % 3;
            float acc = c[17] * (x0 * by3[q]) + c[18] * (x1[a] * y2[t9])
                      + c[19] * (x2[r] * y1[e]) + c[21] * (bx3[q] * y0);
            float s20 = 0.f, s22 = 0.f;
            #pragma unroll
            for (int u = 0; u < 3; ++u) s20 += x2[a*3 + u] * by3[u*9 + t9]; // (2,3,3)
            #pragma unroll
            for (int u = 0; u < 3; ++u) s22 += bx3[r*3 + u] * y2[u*3 + e];  // (3,2,3)
            o3[q] = acc + c[20]*s20 + c[22]*s22;
        }
    }
}

__device__ __forceinline__ void stage_outputs(
    float* __restrict__ B, int f, int h,
    float o0, const float* o1, const float* o2, const float* o3)
{
    if (h == 0) {
        B[f] = o0;
        #pragma unroll
        for (int d = 0; d < 3; ++d) B[64  + f*3 + d] = o1[d];
        #pragma unroll
        for (int t = 0; t < 9; ++t) B[256 + f*9 + t] = o2[t];
    } else {
        #pragma unroll
        for (int q = 0; q < 27; ++q) B[832 + f*27 + q] = o3[q];
    }
}

__global__ __launch_bounds__(128) void wtp_kernel(
    const float* __restrict__ x, const float* __restrict__ y,
    const float* __restrict__ w, float* __restrict__ out)
{
    __shared__ float bufA[2 * HALFROW];   // 20 KB node A (x-half | y-half)
    __shared__ float bufB[2 * HALFROW];   // 20 KB node B

    const int tid   = threadIdx.x;
    const int f     = tid & 63;               // local feature
    const int half  = tid >> 6;               // wave 0 -> l3<=2 ; wave 1 -> l3=3
    const int wbase = half * 256;             // wave-uniform LDS float offset

    const int n0    = (blockIdx.x >> 1) * 2;  // first of the node pair
    const int fbase = (blockIdx.x & 1) << 6;  // 0 or 64

    const float* xA = x + (size_t)n0 * ROW;
    const float* yA = y + (size_t)n0 * ROW;
    const float* xB = xA + ROW;
    const float* yB = yA + ROW;
    float* orowA    = out + (size_t)n0 * ROW;
    float* orowB    = orowA + ROW;

    // per-lane global offsets for the 5 DMA/store issues (packed half-row)
    int goff[5];
    #pragma unroll
    for (int i = 0; i < 5; ++i) {
        const int o = i * 512 + tid * 4;
        int r;
        if      (o < 64)  r = fbase          + o;
        else if (o < 256) r = 128  + fbase*3  + (o - 64);
        else if (o < 832) r = 512  + fbase*9  + (o - 256);
        else              r = 1664 + fbase*27 + (o - 832);
        goff[i] = r;
    }

    // ---- DMA node A (10 loads/wave) ----
    #pragma unroll
    for (int i = 0; i < 5; ++i) {
        GL2LDS(xA + goff[i], bufA + i * 512 + wbase);
        GL2LDS(yA + goff[i], bufA + HALFROW + i * 512 + wbase);
    }
    // ---- weights (23 VMEM loads/lane, retired by the vmcnt(10) below) ----
    float c[23];
    #pragma unroll
    for (int p = 0; p < 23; ++p) c[p] = NORMS[p] * w[p * FF + fbase + f];
    // ---- DMA node B (10 more loads/wave; 20+ outstanding now) ----
    #pragma unroll
    for (int i = 0; i < 5; ++i) {
        GL2LDS(xB + goff[i], bufB + i * 512 + wbase);
        GL2LDS(yB + goff[i], bufB + HALFROW + i * 512 + wbase);
    }

    // retire A-loads + weight loads; leave B's 10 loads in flight
    asm volatile("s_waitcnt vmcnt(10)" ::: "memory");
    __builtin_amdgcn_s_barrier();

    // ================= node A =================
    float o0, o1[3], o2[9], o3[27];
    compute_node(bufA, bufA + HALFROW, c, f, half, o0, o1, o2, o3);

    asm volatile("s_waitcnt lgkmcnt(0)" ::: "memory");
    __builtin_amdgcn_s_barrier();          // all reads of bufA done
    stage_outputs(bufA, f, half, o0, o1, o2, o3);
    asm volatile("s_waitcnt lgkmcnt(0)" ::: "memory");
    __builtin_amdgcn_s_barrier();          // staged outputs visible

    #pragma unroll
    for (int i = 0; i < 5; ++i) {          // 5 NT stores/wave -> in flight
        floatx4 v = *(const floatx4*)(bufA + i * 512 + tid * 4);
        __builtin_nontemporal_store(v, (floatx4*)(orowA + goff[i]));
    }

    // retire B's loads (outstanding: 10 B-loads + 5 A-stores -> keep stores)
    asm volatile("s_waitcnt vmcnt(5)" ::: "memory");
    __builtin_amdgcn_s_barrier();

    // ================= node B =================
    compute_node(bufB, bufB + HALFROW, c, f, half, o0, o1, o2, o3);

    asm volatile("s_waitcnt lgkmcnt(0)" ::: "memory");
    __builtin_amdgcn_s_barrier();          // all reads of bufB done
    stage_outputs(bufB, f, half, o0, o1, o2, o3);
    asm volatile("s_waitcnt lgkmcnt(0)" ::: "memory");
    __builtin_amdgcn_s_barrier();          // staged outputs visible

    #pragma unroll
    for (int i = 0; i < 5; ++i) {
        floatx4 v = *(const floatx4*)(bufB + i * 512 + tid * 4);
        __builtin_nontemporal_store(v, (floatx4*)(orowB + goff[i]));
    }
}

extern "C" void kernel_launch(void* const* d_in, const int* in_sizes, int n_in,
                              void* d_out, int out_size, void* d_ws, size_t ws_size,
                              hipStream_t stream) {
    const float* x = (const float*)d_in[0];
    const float* y = (const float*)d_in[1];
    const float* w = (const float*)d_in[2];
    float* out = (float*)d_out;

    const int n_nodes = in_sizes[0] / ROW;       // 16384
    dim3 grid(n_nodes), block(128);              // node-pair x feature-half
    hipLaunchKernelGGL(wtp_kernel, grid, block, 0, stream, x, y, w, out);
}

// Round 13
// 178.089 us; speedup vs baseline: 1.1338x; 1.0205x over previous
//
#include <hip/hip_runtime.h>

// WeightedTensorProduct: N=16384 nodes, F=128, ranks 0..3 (sizes 1,3,9,27).
// x,y: [N, 5120] f32 (row: [128] | [128][3] | [128][9] | [128][27]).
// weights: [23][128] f32. out: [N, 5120] f32.
//
// CHAMPION (round 7, 177.9 us): half-node per 128-thread block (64 features),
// 32768 one-shot blocks. Coalesced global->LDS DMA (piecewise per-lane global
// offsets, lane-linear LDS dest), rank-0..2 blocks in registers, rank-3 read
// from LDS at use (keeps VGPR ~96 -> no scratch spills), outputs staged back
// through LDS, NT float4 stores reusing the DMA offsets.
// 12-round ledger: all clean structures land 178-202 us; traffic is ideal
// (FETCH/WRITE ~336/336 MB, conflicts 0); effective CU<->mem throughput
// (671 MB reads + 335 MB writes)/178 us = 5.65 TB/s ~ 90% of the 6.29 TB/s
// copy ceiling, with LDS staging + 400 VALU FLOPs/thread on the critical path.

#define FF 128
#define ROW 5120
#define HALFROW 2560   // floats per half-node row (64 features x 40)

typedef float floatx4 __attribute__((ext_vector_type(4)));

__device__ __constant__ float NORMS[23] = {
    1.0f, 1.0f, 2.0f/3.0f, 0.4f,                          // (0,0,0)(1,1,0)(2,2,0)(3,3,0)
    1.0f, 1.0f, 1.0f, 1.0f, 2.0f/3.0f, 2.0f/3.0f,         // l3=1 paths
    1.0f, 0.75f, 1.0f, 1.0f, 1.0f, 1.0f, 0.75f,           // l3=2 paths
    1.0f, 5.0f/9.0f, 5.0f/9.0f, 5.0f/6.0f, 1.0f, 5.0f/6.0f // l3=3 paths
};

#define GL2LDS(g, l)  __builtin_amdgcn_global_load_lds(                      \
        (const __attribute__((address_space(1))) void*)(g),                  \
        (__attribute__((address_space(3))) void*)(l), 16, 0, 0)

// packed half-row float offset o in [0,2560) -> offset within the full row
__device__ __forceinline__ int rowoff(int o, int fbase) {
    if (o < 64)  return fbase       + o;          // rank0: 64 floats
    if (o < 256) return 128 + fbase*3  + (o-64);  // rank1: 192 floats
    if (o < 832) return 512 + fbase*9  + (o-256); // rank2: 576 floats
    return 1664 + fbase*27 + (o-832);             // rank3: 1728 floats
}

__global__ __launch_bounds__(128) void wtp_kernel(
    const float* __restrict__ x, const float* __restrict__ y,
    const float* __restrict__ w, float* __restrict__ out)
{
    __shared__ float buf[2 * HALFROW];   // 20 KB: x-half, y-half (packed)

    const int tid   = threadIdx.x;
    const int f     = tid & 63;               // local feature
    const int half  = tid >> 6;               // wave 0 -> l3=0,1,2 ; wave 1 -> l3=3
    const int wbase = half * 256;             // wave-uniform LDS float offset per issue

    const int n     = blockIdx.x >> 1;
    const int fbase = (blockIdx.x & 1) << 6;  // 0 or 64

    const float* xr = x + (size_t)n * ROW;
    const float* yr = y + (size_t)n * ROW;
    float* orow     = out + (size_t)n * ROW;

    // per-lane global offsets for the 5 DMA/store issues (16B/lane, 2 waves)
    int goff[5];
    #pragma unroll
    for (int i = 0; i < 5; ++i) goff[i] = rowoff(i * 512 + tid * 4, fbase);

    // ---- issue coalesced DMA of both half-rows (packed into LDS) ----
    #pragma unroll
    for (int i = 0; i < 5; ++i) {
        GL2LDS(xr + goff[i], buf + i * 512 + wbase);
        GL2LDS(yr + goff[i], buf + HALFROW + i * 512 + wbase);
    }

    // ---- weights load overlaps the DMA in-flight window ----
    float c[23];
    #pragma unroll
    for (int p = 0; p < 23; ++p) c[p] = NORMS[p] * w[p * FF + fbase + f];

    asm volatile("s_waitcnt vmcnt(0)" ::: "memory");
    __syncthreads();

    // ---- rank 0..2 blocks -> registers; rank-3 stays in LDS ----
    const float* bx = buf;
    const float* by = buf + HALFROW;
    const float x0 = bx[f], y0 = by[f];
    float x1[3], y1[3], x2[9], y2[9];
    #pragma unroll
    for (int j = 0; j < 3; ++j)  x1[j] = bx[64  + f*3 + j];
    #pragma unroll
    for (int j = 0; j < 3; ++j)  y1[j] = by[64  + f*3 + j];
    #pragma unroll
    for (int j = 0; j < 9; ++j)  x2[j] = bx[256 + f*9 + j];
    #pragma unroll
    for (int j = 0; j < 9; ++j)  y2[j] = by[256 + f*9 + j];

    const float* bx3 = bx + 832 + f*27;   // stride 27 (odd) -> conflict-free
    const float* by3 = by + 832 + f*27;

    float o0, o1[3], o2[9], o3[27];

    if (half == 0) {
        // ---- l3 = 0 ----
        {
            float acc = c[0] * (x0 * y0);
            float d3 = 0.f;
            #pragma unroll
            for (int u = 0; u < 3; ++u) d3 += x1[u] * y1[u];
            acc += c[1] * d3;
            float d9 = 0.f;
            #pragma unroll
            for (int t = 0; t < 9; ++t) d9 += x2[t] * y2[t];
            acc += c[2] * d9;
            float d27 = 0.f;
            #pragma unroll
            for (int t = 0; t < 27; ++t) d27 += bx3[t] * by3[t];
            acc += c[3] * d27;
            o0 = acc;
        }
        // ---- l3 = 1 ----
        #pragma unroll
        for (int d = 0; d < 3; ++d) {
            float acc = c[4] * (x0 * y1[d]) + c[5] * (x1[d] * y0);
            float s6 = 0.f, s7 = 0.f, s8 = 0.f, s9 = 0.f;
            #pragma unroll
            for (int u = 0; u < 3; ++u) s6 += x1[u] * y2[u*3 + d];     // (1,2,1)
            #pragma unroll
            for (int u = 0; u < 3; ++u) s7 += x2[d*3 + u] * y1[u];     // (2,1,1)
            #pragma unroll
            for (int t = 0; t < 9; ++t) s8 += x2[t] * by3[t*3 + d];    // (2,3,1)
            #pragma unroll
            for (int t = 0; t < 9; ++t) s9 += bx3[d*9 + t] * y2[t];    // (3,2,1)
            o1[d] = acc + c[6]*s6 + c[7]*s7 + c[8]*s8 + c[9]*s9;
        }
        // ---- l3 = 2 ----  (t = a*3 + d)
        #pragma unroll
        for (int t = 0; t < 9; ++t) {
            const int a = t / 3, d = t % 3;
            float acc = c[10] * (x0 * y2[t]) + c[11] * (x1[a] * y1[d])
                      + c[13] * (x2[t] * y0);
            float s12 = 0.f, s14 = 0.f, s15 = 0.f, s16 = 0.f;
            #pragma unroll
            for (int u = 0; u < 3; ++u) s12 += x1[u] * by3[u*9 + t];       // (1,3,2)
            #pragma unroll
            for (int u = 0; u < 3; ++u) s14 += x2[a*3 + u] * y2[u*3 + d];  // (2,2,2)
            #pragma unroll
            for (int u = 0; u < 3; ++u) s15 += bx3[t*3 + u] * y1[u];       // (3,1,2)
            #pragma unroll
            for (int s = 0; s < 9; ++s) s16 += bx3[a*9 + s] * by3[s*3 + d];// (3,3,2)
            o2[t] = acc + c[12]*s12 + c[14]*s14 + c[15]*s15 + c[16]*s16;
        }
    } else {
        // ---- l3 = 3 ----  (q = a*9 + t9, also q = r*3 + e)
        #pragma unroll
        for (int q = 0; q < 27; ++q) {
            const int a = q / 9, t9 = q % 9, r = q / 3, e = q % 3;
            float acc = c[17] * (x0 * by3[q]) + c[18] * (x1[a] * y2[t9])
                      + c[19] * (x2[r] * y1[e]) + c[21] * (bx3[q] * y0);
            float s20 = 0.f, s22 = 0.f;
            #pragma unroll
            for (int u = 0; u < 3; ++u) s20 += x2[a*3 + u] * by3[u*9 + t9]; // (2,3,3)
            #pragma unroll
            for (int u = 0; u < 3; ++u) s22 += bx3[r*3 + u] * y2[u*3 + e];  // (3,2,3)
            o3[q] = acc + c[20]*s20 + c[22]*s22;
        }
    }
    __syncthreads();   // all LDS reads of x/y done; safe to overwrite x-region

    // ---- stage outputs into LDS x-region (odd strides, conflict-free) ----
    if (half == 0) {
        buf[f] = o0;
        #pragma unroll
        for (int d = 0; d < 3; ++d) buf[64  + f*3 + d] = o1[d];
        #pragma unroll
        for (int t = 0; t < 9; ++t) buf[256 + f*9 + t] = o2[t];
    } else {
        #pragma unroll
        for (int q = 0; q < 27; ++q) buf[832 + f*27 + q] = o3[q];
    }
    __syncthreads();

    // ---- coalesced NONTEMPORAL float4 store (same offsets as the DMA) ----
    #pragma unroll
    for (int i = 0; i < 5; ++i) {
        floatx4 v = *(const floatx4*)(buf + i * 512 + tid * 4);
        __builtin_nontemporal_store(v, (floatx4*)(orow + goff[i]));
    }
}

extern "C" void kernel_launch(void* const* d_in, const int* in_sizes, int n_in,
                              void* d_out, int out_size, void* d_ws, size_t ws_size,
                              hipStream_t stream) {
    const float* x = (const float*)d_in[0];
    const float* y = (const float*)d_in[1];
    const float* w = (const float*)d_in[2];
    float* out = (float*)d_out;

    const int n_nodes = in_sizes[0] / ROW;       // 16384
    dim3 grid(n_nodes * 2), block(128);          // half-node per block
    hipLaunchKernelGGL(wtp_kernel, grid, block, 0, stream, x, y, w, out);
}